// Round 13
// baseline (151.628 us; speedup 1.0000x reference)
//
#include <hip/hip_runtime.h>
#include <math.h>

#define IN_CH 128
#define H1N 8
#define C1N 16
#define C2N 64
#define NEG_SLOPE 0.2f

#define BKT_SHIFT 7                 // 128 nodes per bucket
#define BKT_NODES (1 << BKT_SHIFT)
#define NBLK 128                    // blocks for count/bin passes

typedef unsigned short ushortT;

__device__ __forceinline__ ushortT f2bf(float f) {
    unsigned u = __float_as_uint(f);
    unsigned r = u + 0x7FFFu + ((u >> 16) & 1u);
    return (ushortT)(r >> 16);
}
__device__ __forceinline__ float bf2f(ushortT b) {
    return __uint_as_float(((unsigned)b) << 16);
}
__device__ __forceinline__ float leaky(float x) {
    return (x > 0.f) ? x : NEG_SLOPE * x;
}

// ---------------- CSR build: deterministic counting sort, no global atomics ----------------

__global__ __launch_bounds__(512) void k_cnt(const int* __restrict__ src,
                                             const int* __restrict__ dst,
                                             int E, int N, int* __restrict__ cnt) {
    __shared__ int hist[512];
    int blk = blockIdx.x, t = threadIdx.x;
    int nb = (N + BKT_NODES - 1) >> BKT_SHIFT;
    if (t < nb) hist[t] = 0;
    __syncthreads();
    int Etot = E + N;
    int chunk = (Etot + gridDim.x - 1) / gridDim.x;
    int lo = blk * chunk;
    int hi = lo + chunk; if (hi > Etot) hi = Etot;
    for (int i = lo + t; i < hi; i += 512) {
        int d = (i < E) ? dst[i] : (i - E);
        atomicAdd(&hist[d >> BKT_SHIFT], 1);
    }
    __syncthreads();
    if (t < nb) cnt[t * NBLK + blk] = hist[t];
}

__global__ __launch_bounds__(NBLK) void k_scanrel(int* __restrict__ cnt,
                                                  int* __restrict__ bucketTotal) {
    __shared__ int sh[NBLK];
    int b = blockIdx.x, t = threadIdx.x;
    sh[t] = cnt[b * NBLK + t];
    __syncthreads();
    for (int off = 1; off < NBLK; off <<= 1) {
        int v = (t >= off) ? sh[t - off] : 0;
        __syncthreads();
        sh[t] += v;
        __syncthreads();
    }
    if (t == NBLK - 1) bucketTotal[b] = sh[t];
    cnt[b * NBLK + t] = (t == 0) ? 0 : sh[t - 1];
}

__global__ __launch_bounds__(512) void k_scanbucket(const int* __restrict__ bucketTotal,
                                                    int nb, int* __restrict__ bBase,
                                                    int N, int* __restrict__ offsets) {
    __shared__ int sh[512];
    int t = threadIdx.x;
    sh[t] = (t < nb) ? bucketTotal[t] : 0;
    __syncthreads();
    for (int off = 1; off < 512; off <<= 1) {
        int v = (t >= off) ? sh[t - off] : 0;
        __syncthreads();
        sh[t] += v;
        __syncthreads();
    }
    if (t < nb) bBase[t] = (t == 0) ? 0 : sh[t - 1];
    if (t == 511) { bBase[nb] = sh[511]; offsets[N] = sh[511]; }
}

__global__ __launch_bounds__(512) void k_bin(const int* __restrict__ src,
                                             const int* __restrict__ dst,
                                             int E, int N,
                                             const int* __restrict__ cnt,
                                             const int* __restrict__ bBase,
                                             unsigned* __restrict__ pair) {
    __shared__ int cur[512];
    int blk = blockIdx.x, t = threadIdx.x;
    int nb = (N + BKT_NODES - 1) >> BKT_SHIFT;
    if (t < nb) cur[t] = bBase[t] + cnt[t * NBLK + blk];
    __syncthreads();
    int Etot = E + N;
    int chunk = (Etot + gridDim.x - 1) / gridDim.x;
    int lo = blk * chunk;
    int hi = lo + chunk; if (hi > Etot) hi = Etot;
    for (int i = lo + t; i < hi; i += 512) {
        int s, d;
        if (i < E) { s = src[i]; d = dst[i]; }
        else       { s = d = i - E; }
        int b = d >> BKT_SHIFT;
        int pos = atomicAdd(&cur[b], 1);
        pair[pos] = ((unsigned)(d & (BKT_NODES - 1)) << 16) | (unsigned)s;
    }
}

__global__ __launch_bounds__(256) void k_csr_local(const unsigned* __restrict__ pair,
                                                   const int* __restrict__ bBase,
                                                   int N, int* __restrict__ offsets,
                                                   ushortT* __restrict__ csr) {
    __shared__ int hist[BKT_NODES];
    __shared__ int loff[BKT_NODES];
    int b = blockIdx.x;
    int t = threadIdx.x;
    int base = bBase[b];
    int cnt = bBase[b + 1] - base;
    const unsigned* pp = pair + base;

    if (t < BKT_NODES) hist[t] = 0;
    __syncthreads();
    for (int i = t; i < cnt; i += 256) atomicAdd(&hist[pp[i] >> 16], 1);
    __syncthreads();
    if (t < BKT_NODES) loff[t] = hist[t];
    __syncthreads();
    for (int off = 1; off < BKT_NODES; off <<= 1) {
        int v = 0;
        if (t < BKT_NODES && t >= off) v = loff[t - off];
        __syncthreads();
        if (t < BKT_NODES) loff[t] += v;
        __syncthreads();
    }
    int node0 = b << BKT_SHIFT;
    if (t < BKT_NODES) {
        int excl = (t == 0) ? 0 : loff[t - 1];
        hist[t] = excl;
        int g = node0 + t;
        if (g < N) offsets[g] = base + excl;
    }
    __syncthreads();
    for (int i = t; i < cnt; i += 256) {
        unsigned pk = pp[i];
        int pos = atomicAdd(&hist[pk >> 16], 1);
        csr[base + pos] = (ushortT)(pk & 0xFFFFu);
    }
}

// ---------------- GEMM + fused attention coefficients ----------------

template <int KOUT, int HEADS, bool BFIN>
__global__ __launch_bounds__(256) void k_gemm_att(const void* __restrict__ Av,
                                                  const float* __restrict__ W,
                                                  const float* __restrict__ att_s,
                                                  const float* __restrict__ att_d,
                                                  int N, ushortT* __restrict__ Cbf,
                                                  float* __restrict__ as_,
                                                  float* __restrict__ ad_) {
    constexpr int CG  = KOUT / 4;
    constexpr int TY  = 256 / CG;
    constexpr int RPT = 64 / TY;
    constexpr int RW  = (KOUT / HEADS) / 4;
    static_assert(RW == 4 || RW == 16, "reduce width");
    __shared__ float As[64][16];
    __shared__ float Ws[16][KOUT];
    int t = threadIdx.x;
    int row0 = blockIdx.x * 64;
    int tx = t % CG, ty = t / CG;

    float4 acc[RPT];
#pragma unroll
    for (int i = 0; i < RPT; ++i) acc[i] = make_float4(0.f, 0.f, 0.f, 0.f);

    for (int k0 = 0; k0 < IN_CH; k0 += 16) {
        {
            int r  = t >> 2;
            int cc = (t & 3) * 4;
            int gr = row0 + r;
            float4 v = make_float4(0.f, 0.f, 0.f, 0.f);
            if (gr < N) {
                if constexpr (BFIN) {
                    const ushortT* A = (const ushortT*)Av;
                    ushort4 u = *(const ushort4*)(A + (size_t)gr * IN_CH + k0 + cc);
                    v.x = bf2f(u.x); v.y = bf2f(u.y); v.z = bf2f(u.z); v.w = bf2f(u.w);
                } else {
                    const float* A = (const float*)Av;
                    v = *(const float4*)(A + (size_t)gr * IN_CH + k0 + cc);
                }
            }
            *(float4*)(&As[r][cc]) = v;
        }
        {
            constexpr int TOT = 16 * KOUT / 4;
            for (int idx = t; idx < TOT; idx += 256) {
                int rr = idx / (KOUT / 4);
                int cc = (idx % (KOUT / 4)) * 4;
                *(float4*)(&Ws[rr][cc]) = *(const float4*)(W + (size_t)(k0 + rr) * KOUT + cc);
            }
        }
        __syncthreads();
#pragma unroll
        for (int kk = 0; kk < 16; ++kk) {
            float4 w = *(const float4*)(&Ws[kk][tx * 4]);
#pragma unroll
            for (int i = 0; i < RPT; ++i) {
                float a = As[ty * RPT + i][kk];
                acc[i].x += a * w.x; acc[i].y += a * w.y;
                acc[i].z += a * w.z; acc[i].w += a * w.w;
            }
        }
        __syncthreads();
    }

    float4 s4 = *(const float4*)(att_s + tx * 4);
    float4 d4 = *(const float4*)(att_d + tx * 4);
#pragma unroll
    for (int i = 0; i < RPT; ++i) {
        int gr = row0 + ty * RPT + i;
        float as = acc[i].x * s4.x + acc[i].y * s4.y + acc[i].z * s4.z + acc[i].w * s4.w;
        float ad = acc[i].x * d4.x + acc[i].y * d4.y + acc[i].z * d4.z + acc[i].w * d4.w;
#pragma unroll
        for (int o = 1; o < RW; o <<= 1) {
            as += __shfl_xor(as, o);
            ad += __shfl_xor(ad, o);
        }
        if (gr < N) {
            ushort4 pk;
            pk.x = f2bf(acc[i].x); pk.y = f2bf(acc[i].y);
            pk.z = f2bf(acc[i].z); pk.w = f2bf(acc[i].w);
            *(ushort4*)(Cbf + (size_t)gr * KOUT + tx * 4) = pk;
            if ((tx % RW) == 0) {
                int h = tx / RW;
                as_[(size_t)gr * HEADS + h] = as;
                ad_[(size_t)gr * HEADS + h] = ad;
            }
        }
    }
}

// ---------------- layer 1 aggregation (+bias +ELU) ----------------
// one wave per node; 16-edge main batches (two independent producer exps ->
// one latency round-trip serves 16 gathers); tail cascade 8 -> 4 -> scalar.
// Output h2in bf16.

__global__ void k_agg1(const ushortT* __restrict__ h1bf,
                       const float* __restrict__ as1, const float* __restrict__ ad1,
                       const int* __restrict__ offsets, const ushortT* __restrict__ csr,
                       const float* __restrict__ b1,
                       int N, ushortT* __restrict__ h2in) {
    int wid  = (blockIdx.x * blockDim.x + threadIdx.x) >> 6;
    int lane = threadIdx.x & 63;
    if (wid >= N) return;
    int v = wid;
    int hc = lane >> 3;               // consumer head
    int hp = lane & 7;                // producer head
    int ep = lane >> 3;               // producer edge in batch
    float adc = ad1[v * H1N + hc];
    float adp = ad1[v * H1N + hp];
    float denom = 0.f, acc0 = 0.f, acc1 = 0.f;
    int beg = offsets[v], end = offsets[v + 1];
    int j = beg;
    for (; j + 16 <= end; j += 16) {
        int sE0 = csr[j + ep];
        int sE1 = csr[j + 8 + ep];
        float a0 = as1[sE0 * H1N + hp];
        float a1 = as1[sE1 * H1N + hp];
        float pp0 = __expf(leaky(a0 + adp));
        float pp1 = __expf(leaky(a1 + adp));
#pragma unroll
        for (int e = 0; e < 16; ++e) {
            int srcl = (e & 7) * 8 + hc;
            float pe = (e < 8) ? __shfl(pp0, srcl) : __shfl(pp1, srcl);
            int   se = (e < 8) ? __shfl(sE0, srcl) : __shfl(sE1, srcl);
            unsigned q = *(const unsigned*)(h1bf + (size_t)se * IN_CH + lane * 2);
            denom += pe;
            acc0 = fmaf(pe, bf2f((ushortT)(q & 0xFFFFu)), acc0);
            acc1 = fmaf(pe, bf2f((ushortT)(q >> 16)), acc1);
        }
    }
    if (j + 8 <= end) {
        int sE = csr[j + ep];
        float a = as1[sE * H1N + hp];
        float pp = __expf(leaky(a + adp));
#pragma unroll
        for (int e = 0; e < 8; ++e) {
            int srcl = e * 8 + hc;
            float pe = __shfl(pp, srcl);
            int   se = __shfl(sE, srcl);
            unsigned q = *(const unsigned*)(h1bf + (size_t)se * IN_CH + lane * 2);
            denom += pe;
            acc0 = fmaf(pe, bf2f((ushortT)(q & 0xFFFFu)), acc0);
            acc1 = fmaf(pe, bf2f((ushortT)(q >> 16)), acc1);
        }
        j += 8;
    }
    if (j + 4 <= end) {
        int ep4 = (lane >> 3) & 3;
        int sE = csr[j + ep4];
        float a = as1[sE * H1N + hp];
        float pp = __expf(leaky(a + adp));
#pragma unroll
        for (int e = 0; e < 4; ++e) {
            int srcl = e * 8 + hc;
            float pe = __shfl(pp, srcl);
            int   se = __shfl(sE, srcl);
            unsigned q = *(const unsigned*)(h1bf + (size_t)se * IN_CH + lane * 2);
            denom += pe;
            acc0 = fmaf(pe, bf2f((ushortT)(q & 0xFFFFu)), acc0);
            acc1 = fmaf(pe, bf2f((ushortT)(q >> 16)), acc1);
        }
        j += 4;
    }
    for (; j < end; ++j) {
        int s = csr[j];
        float a = as1[s * H1N + hc];
        unsigned q = *(const unsigned*)(h1bf + (size_t)s * IN_CH + lane * 2);
        float p = __expf(leaky(a + adc));
        denom += p;
        acc0 = fmaf(p, bf2f((ushortT)(q & 0xFFFFu)), acc0);
        acc1 = fmaf(p, bf2f((ushortT)(q >> 16)), acc1);
    }
    float inv = 1.f / (denom + 1e-16f);
    float o0 = acc0 * inv + b1[lane * 2];
    float o1 = acc1 * inv + b1[lane * 2 + 1];
    o0 = (o0 > 0.f) ? o0 : expm1f(o0);
    o1 = (o1 > 0.f) ? o1 : expm1f(o1);
    unsigned pk = ((unsigned)f2bf(o1) << 16) | (unsigned)f2bf(o0);
    *(unsigned*)(h2in + (size_t)v * IN_CH + lane * 2) = pk;
}

// ---------------- layer 2 aggregation (+bias) + log_softmax ----------------
// 2 nodes per wave (32-lane halves); 16-edge main batches per half
// (32 outstanding gathers/wave); tail cascade 8 -> scalar-ish.

__global__ __launch_bounds__(256) void k_agg2(const ushortT* __restrict__ h2bf,
                       const float* __restrict__ as2, const float* __restrict__ ad2,
                       const int* __restrict__ offsets, const ushortT* __restrict__ csr,
                       const float* __restrict__ b2,
                       int N, float* __restrict__ out) {
    int wid  = (blockIdx.x * blockDim.x + threadIdx.x) >> 6;
    int lane = threadIdx.x & 63;
    int half = lane >> 5;
    int v = wid * 2 + half;
    bool alive = (v < N);
    int c2 = (lane & 31) * 2;          // channels c2, c2+1

    float ad = 0.f;
    int beg = 0, end = 0;
    if (alive) {
        ad = ad2[v];
        beg = offsets[v];
        end = offsets[v + 1];
    }
    float denom = 0.f, acc0 = 0.f, acc1 = 0.f;
    int j = beg;
    for (; j + 16 <= end; j += 16) {
        int sE = csr[j + (lane & 15)];
        float p = __expf(leaky(as2[sE] + ad));
#pragma unroll
        for (int e = 0; e < 16; ++e) {
            int srcl = (lane & 32) + e;
            float pe = __shfl(p, srcl);
            int   se = __shfl(sE, srcl);
            unsigned q = *(const unsigned*)(h2bf + (size_t)se * C2N + c2);
            denom += pe;
            acc0 = fmaf(pe, bf2f((ushortT)(q & 0xFFFFu)), acc0);
            acc1 = fmaf(pe, bf2f((ushortT)(q >> 16)), acc1);
        }
    }
    if (j + 8 <= end) {
        int sE = csr[j + (lane & 7)];
        float p = __expf(leaky(as2[sE] + ad));
#pragma unroll
        for (int e = 0; e < 8; ++e) {
            int srcl = (lane & 32) + e;
            float pe = __shfl(p, srcl);
            int   se = __shfl(sE, srcl);
            unsigned q = *(const unsigned*)(h2bf + (size_t)se * C2N + c2);
            denom += pe;
            acc0 = fmaf(pe, bf2f((ushortT)(q & 0xFFFFu)), acc0);
            acc1 = fmaf(pe, bf2f((ushortT)(q >> 16)), acc1);
        }
        j += 8;
    }
    if (j < end) {                     // tail <8
        int m = end - j;
        int ep = lane & 7;
        int sE = 0;
        float p = 0.f;
        if (ep < m) {
            sE = csr[j + ep];
            p = __expf(leaky(as2[sE] + ad));
        }
        for (int e = 0; e < m; ++e) {
            int srcl = (lane & 32) + e;
            float pe = __shfl(p, srcl);
            int   se = __shfl(sE, srcl);
            unsigned q = *(const unsigned*)(h2bf + (size_t)se * C2N + c2);
            denom += pe;
            acc0 = fmaf(pe, bf2f((ushortT)(q & 0xFFFFu)), acc0);
            acc1 = fmaf(pe, bf2f((ushortT)(q >> 16)), acc1);
        }
    }
    float inv = 1.f / (denom + 1e-16f);
    float o0 = acc0 * inv + b2[c2];
    float o1 = acc1 * inv + b2[c2 + 1];
    float mx = fmaxf(o0, o1);
#pragma unroll
    for (int off = 16; off >= 1; off >>= 1) mx = fmaxf(mx, __shfl_xor(mx, off));
    float se2 = __expf(o0 - mx) + __expf(o1 - mx);
#pragma unroll
    for (int off = 16; off >= 1; off >>= 1) se2 += __shfl_xor(se2, off);
    if (alive) {
        float lse = logf(se2);
        float2 ov; ov.x = o0 - mx - lse; ov.y = o1 - mx - lse;
        *(float2*)(out + (size_t)v * C2N + c2) = ov;
    }
}

// ---------------- launch ----------------

extern "C" void kernel_launch(void* const* d_in, const int* in_sizes, int n_in,
                              void* d_out, int out_size, void* d_ws, size_t ws_size,
                              hipStream_t stream) {
    const float* x      = (const float*)d_in[0];
    const int*   ei     = (const int*)d_in[1];
    const float* W1     = (const float*)d_in[2];
    const float* att_s1 = (const float*)d_in[3];
    const float* att_d1 = (const float*)d_in[4];
    const float* b1     = (const float*)d_in[5];
    const float* W2     = (const float*)d_in[6];
    const float* att_s2 = (const float*)d_in[7];
    const float* att_d2 = (const float*)d_in[8];
    const float* b2     = (const float*)d_in[9];

    int N = in_sizes[0] / IN_CH;
    int E = in_sizes[1] / 2;
    const int* srcA = ei;
    const int* dstA = ei + E;
    int Etot = E + N;
    int nb = (N + BKT_NODES - 1) >> BKT_SHIFT;

    char* p = (char*)d_ws;
    auto carve = [&](size_t bytes) {
        void* r = (void*)p;
        p += (bytes + 255) & ~(size_t)255;
        return r;
    };
    ushortT* h1bf = (ushortT*)carve((size_t)N * IN_CH * 2);
    ushortT* h2bf = (ushortT*)carve((size_t)N * C2N * 2);
    ushortT* h2in = (ushortT*)carve((size_t)N * IN_CH * 2);
    float* as1  = (float*)carve((size_t)N * H1N * 4);
    float* ad1  = (float*)carve((size_t)N * H1N * 4);
    float* as2  = (float*)carve((size_t)N * 4);
    float* ad2  = (float*)carve((size_t)N * 4);
    int* offsets     = (int*)carve((size_t)(N + 1) * 4);
    ushortT* csr     = (ushortT*)carve((size_t)(Etot + 32) * 2);  // +pad for batch overread
    int* cnt         = (int*)carve((size_t)nb * NBLK * 4);
    int* bucketTotal = (int*)carve((size_t)nb * 4);
    int* bBase       = (int*)carve((size_t)(nb + 1) * 4);
    unsigned* pair   = (unsigned*)carve((size_t)Etot * 4);

    // CSR build (deterministic counting sort; no global atomics)
    k_cnt<<<NBLK, 512, 0, stream>>>(srcA, dstA, E, N, cnt);
    k_scanrel<<<nb, NBLK, 0, stream>>>(cnt, bucketTotal);
    k_scanbucket<<<1, 512, 0, stream>>>(bucketTotal, nb, bBase, N, offsets);
    k_bin<<<NBLK, 512, 0, stream>>>(srcA, dstA, E, N, cnt, bBase, pair);
    k_csr_local<<<nb, 256, 0, stream>>>(pair, bBase, N, offsets, csr);

    // layer 1
    k_gemm_att<128, 8, false><<<(N + 63) / 64, 256, 0, stream>>>(x, W1, att_s1, att_d1,
                                                                 N, h1bf, as1, ad1);
    k_agg1<<<(N * 64 + 255) / 256, 256, 0, stream>>>(h1bf, as1, ad1, offsets, csr, b1, N, h2in);

    // layer 2
    k_gemm_att<64, 1, true><<<(N + 63) / 64, 256, 0, stream>>>(h2in, W2, att_s2, att_d2,
                                                               N, h2bf, as2, ad2);
    k_agg2<<<(N * 32 + 255) / 256, 256, 0, stream>>>(h2bf, as2, ad2, offsets, csr, b2,
                                                     N, (float*)d_out);
}

// Round 14
// 138.247 us; speedup vs baseline: 1.0968x; 1.0968x over previous
//
#include <hip/hip_runtime.h>
#include <math.h>

#define IN_CH 128
#define H1N 8
#define C1N 16
#define C2N 64
#define NEG_SLOPE 0.2f

#define BKT_SHIFT 7                 // 128 nodes per bucket
#define BKT_NODES (1 << BKT_SHIFT)
#define NBLK 128                    // blocks for count/bin passes

typedef unsigned short ushortT;
typedef short bf16x8 __attribute__((ext_vector_type(8)));
typedef float f32x4 __attribute__((ext_vector_type(4)));

__device__ __forceinline__ ushortT f2bf(float f) {
    unsigned u = __float_as_uint(f);
    unsigned r = u + 0x7FFFu + ((u >> 16) & 1u);
    return (ushortT)(r >> 16);
}
__device__ __forceinline__ float bf2f(ushortT b) {
    return __uint_as_float(((unsigned)b) << 16);
}
__device__ __forceinline__ float leaky(float x) {
    return (x > 0.f) ? x : NEG_SLOPE * x;
}

// ---------------- CSR build: deterministic counting sort, no global atomics ----------------

__global__ __launch_bounds__(512) void k_cnt(const int* __restrict__ src,
                                             const int* __restrict__ dst,
                                             int E, int N, int* __restrict__ cnt) {
    __shared__ int hist[512];
    int blk = blockIdx.x, t = threadIdx.x;
    int nb = (N + BKT_NODES - 1) >> BKT_SHIFT;
    if (t < nb) hist[t] = 0;
    __syncthreads();
    int Etot = E + N;
    int chunk = (Etot + gridDim.x - 1) / gridDim.x;
    int lo = blk * chunk;
    int hi = lo + chunk; if (hi > Etot) hi = Etot;
    for (int i = lo + t; i < hi; i += 512) {
        int d = (i < E) ? dst[i] : (i - E);
        atomicAdd(&hist[d >> BKT_SHIFT], 1);
    }
    __syncthreads();
    if (t < nb) cnt[t * NBLK + blk] = hist[t];
}

__global__ __launch_bounds__(NBLK) void k_scanrel(int* __restrict__ cnt,
                                                  int* __restrict__ bucketTotal) {
    __shared__ int sh[NBLK];
    int b = blockIdx.x, t = threadIdx.x;
    sh[t] = cnt[b * NBLK + t];
    __syncthreads();
    for (int off = 1; off < NBLK; off <<= 1) {
        int v = (t >= off) ? sh[t - off] : 0;
        __syncthreads();
        sh[t] += v;
        __syncthreads();
    }
    if (t == NBLK - 1) bucketTotal[b] = sh[t];
    cnt[b * NBLK + t] = (t == 0) ? 0 : sh[t - 1];
}

__global__ __launch_bounds__(512) void k_scanbucket(const int* __restrict__ bucketTotal,
                                                    int nb, int* __restrict__ bBase,
                                                    int N, int* __restrict__ offsets) {
    __shared__ int sh[512];
    int t = threadIdx.x;
    sh[t] = (t < nb) ? bucketTotal[t] : 0;
    __syncthreads();
    for (int off = 1; off < 512; off <<= 1) {
        int v = (t >= off) ? sh[t - off] : 0;
        __syncthreads();
        sh[t] += v;
        __syncthreads();
    }
    if (t < nb) bBase[t] = (t == 0) ? 0 : sh[t - 1];
    if (t == 511) { bBase[nb] = sh[511]; offsets[N] = sh[511]; }
}

__global__ __launch_bounds__(512) void k_bin(const int* __restrict__ src,
                                             const int* __restrict__ dst,
                                             int E, int N,
                                             const int* __restrict__ cnt,
                                             const int* __restrict__ bBase,
                                             unsigned* __restrict__ pair) {
    __shared__ int cur[512];
    int blk = blockIdx.x, t = threadIdx.x;
    int nb = (N + BKT_NODES - 1) >> BKT_SHIFT;
    if (t < nb) cur[t] = bBase[t] + cnt[t * NBLK + blk];
    __syncthreads();
    int Etot = E + N;
    int chunk = (Etot + gridDim.x - 1) / gridDim.x;
    int lo = blk * chunk;
    int hi = lo + chunk; if (hi > Etot) hi = Etot;
    for (int i = lo + t; i < hi; i += 512) {
        int s, d;
        if (i < E) { s = src[i]; d = dst[i]; }
        else       { s = d = i - E; }
        int b = d >> BKT_SHIFT;
        int pos = atomicAdd(&cur[b], 1);
        pair[pos] = ((unsigned)(d & (BKT_NODES - 1)) << 16) | (unsigned)s;
    }
}

__global__ __launch_bounds__(256) void k_csr_local(const unsigned* __restrict__ pair,
                                                   const int* __restrict__ bBase,
                                                   int N, int* __restrict__ offsets,
                                                   ushortT* __restrict__ csr) {
    __shared__ int hist[BKT_NODES];
    __shared__ int loff[BKT_NODES];
    int b = blockIdx.x;
    int t = threadIdx.x;
    int base = bBase[b];
    int cnt = bBase[b + 1] - base;
    const unsigned* pp = pair + base;

    if (t < BKT_NODES) hist[t] = 0;
    __syncthreads();
    for (int i = t; i < cnt; i += 256) atomicAdd(&hist[pp[i] >> 16], 1);
    __syncthreads();
    if (t < BKT_NODES) loff[t] = hist[t];
    __syncthreads();
    for (int off = 1; off < BKT_NODES; off <<= 1) {
        int v = 0;
        if (t < BKT_NODES && t >= off) v = loff[t - off];
        __syncthreads();
        if (t < BKT_NODES) loff[t] += v;
        __syncthreads();
    }
    int node0 = b << BKT_SHIFT;
    if (t < BKT_NODES) {
        int excl = (t == 0) ? 0 : loff[t - 1];
        hist[t] = excl;
        int g = node0 + t;
        if (g < N) offsets[g] = base + excl;
    }
    __syncthreads();
    for (int i = t; i < cnt; i += 256) {
        unsigned pk = pp[i];
        int pos = atomicAdd(&hist[pk >> 16], 1);
        csr[base + pos] = (ushortT)(pk & 0xFFFFu);
    }
}

// ---------------- MFMA GEMM (bf16) + fused attention coefficients ----------------
// C[N,KOUT](bf16) = A[N,128] @ W[128,KOUT]; A cast to bf16 in staging.
// 256 thr = 4 waves; tile 64 rows; wave w computes rows w*16..w*16+15 via
// mfma_f32_16x16x32_bf16 over NT=KOUT/16 col-tiles, K=128 in 4 steps.
// C/D layout: col=lane&15, row=(lane>>4)*4+reg (verified mapping).

template <int KOUT, int HEADS, bool BFIN>
__global__ __launch_bounds__(256) void k_gemm_att(const void* __restrict__ Av,
                                                  const float* __restrict__ W,
                                                  const float* __restrict__ att_s,
                                                  const float* __restrict__ att_d,
                                                  int N, ushortT* __restrict__ Cbf,
                                                  float* __restrict__ as_,
                                                  float* __restrict__ ad_) {
    constexpr int NT = KOUT / 16;          // col-tiles
    constexpr int LDK = IN_CH + 8;         // padded row (bf16) -> 272B, 16B-aligned
    __shared__ ushortT Alds[64][LDK];
    __shared__ ushortT Wlds[KOUT][LDK];    // W transposed: Wlds[n][k]
    int t = threadIdx.x;
    int row0 = blockIdx.x * 64;
    int w    = t >> 6;
    int lane = t & 63;
    int lm   = lane & 15;
    int lg   = lane >> 4;

    // stage A tile (64 x 128) -> bf16
    for (int idx = t; idx < 64 * 32; idx += 256) {
        int r  = idx >> 5;
        int c4 = (idx & 31) << 2;
        int gr = row0 + r;
        ushort4 u; u.x = 0; u.y = 0; u.z = 0; u.w = 0;
        if (gr < N) {
            if constexpr (BFIN) {
                u = *(const ushort4*)((const ushortT*)Av + (size_t)gr * IN_CH + c4);
            } else {
                float4 v = *(const float4*)((const float*)Av + (size_t)gr * IN_CH + c4);
                u.x = f2bf(v.x); u.y = f2bf(v.y); u.z = f2bf(v.z); u.w = f2bf(v.w);
            }
        }
        *(ushort4*)(&Alds[r][c4]) = u;
    }
    // stage W transposed (k-major in rows of Wlds[n])
    for (int idx = t; idx < IN_CH * KOUT; idx += 256) {
        int k = idx / KOUT;
        int n = idx % KOUT;
        Wlds[n][k] = f2bf(W[(size_t)k * KOUT + n]);
    }
    __syncthreads();

    f32x4 acc[NT];
#pragma unroll
    for (int ct = 0; ct < NT; ++ct) acc[ct] = (f32x4){0.f, 0.f, 0.f, 0.f};

    int ar = w * 16 + lm;
#pragma unroll
    for (int ks = 0; ks < 4; ++ks) {
        int kb = ks * 32 + lg * 8;
        bf16x8 af = *(const bf16x8*)(&Alds[ar][kb]);
#pragma unroll
        for (int ct = 0; ct < NT; ++ct) {
            bf16x8 bf = *(const bf16x8*)(&Wlds[ct * 16 + lm][kb]);
            acc[ct] = __builtin_amdgcn_mfma_f32_16x16x32_bf16(af, bf, acc[ct], 0, 0, 0);
        }
    }

    // epilogue: bf16 store + attention partials
    float asp0 = 0.f, asp1 = 0.f, asp2 = 0.f, asp3 = 0.f;
    float adp0 = 0.f, adp1 = 0.f, adp2 = 0.f, adp3 = 0.f;
#pragma unroll
    for (int ct = 0; ct < NT; ++ct) {
        int gcol = ct * 16 + lm;
        float sc = att_s[gcol];
        float dc = att_d[gcol];
        float c0 = acc[ct][0], c1 = acc[ct][1], c2 = acc[ct][2], c3 = acc[ct][3];
#pragma unroll
        for (int i = 0; i < 4; ++i) {
            int gr = row0 + w * 16 + lg * 4 + i;
            if (gr < N) Cbf[(size_t)gr * KOUT + gcol] = f2bf(acc[ct][i]);
        }
        if constexpr (HEADS == 1) {
            asp0 = fmaf(c0, sc, asp0); asp1 = fmaf(c1, sc, asp1);
            asp2 = fmaf(c2, sc, asp2); asp3 = fmaf(c3, sc, asp3);
            adp0 = fmaf(c0, dc, adp0); adp1 = fmaf(c1, dc, adp1);
            adp2 = fmaf(c2, dc, adp2); adp3 = fmaf(c3, dc, adp3);
        } else {
            float r0 = c0 * sc, r1 = c1 * sc, r2 = c2 * sc, r3 = c3 * sc;
            float q0 = c0 * dc, q1 = c1 * dc, q2 = c2 * dc, q3 = c3 * dc;
#pragma unroll
            for (int off = 1; off < 16; off <<= 1) {
                r0 += __shfl_xor(r0, off); r1 += __shfl_xor(r1, off);
                r2 += __shfl_xor(r2, off); r3 += __shfl_xor(r3, off);
                q0 += __shfl_xor(q0, off); q1 += __shfl_xor(q1, off);
                q2 += __shfl_xor(q2, off); q3 += __shfl_xor(q3, off);
            }
            if (lm == 0) {
                int grb = row0 + w * 16 + lg * 4;
                if (grb + 0 < N) { as_[(size_t)(grb + 0) * HEADS + ct] = r0; ad_[(size_t)(grb + 0) * HEADS + ct] = q0; }
                if (grb + 1 < N) { as_[(size_t)(grb + 1) * HEADS + ct] = r1; ad_[(size_t)(grb + 1) * HEADS + ct] = q1; }
                if (grb + 2 < N) { as_[(size_t)(grb + 2) * HEADS + ct] = r2; ad_[(size_t)(grb + 2) * HEADS + ct] = q2; }
                if (grb + 3 < N) { as_[(size_t)(grb + 3) * HEADS + ct] = r3; ad_[(size_t)(grb + 3) * HEADS + ct] = q3; }
            }
        }
    }
    if constexpr (HEADS == 1) {
#pragma unroll
        for (int off = 1; off < 16; off <<= 1) {
            asp0 += __shfl_xor(asp0, off); asp1 += __shfl_xor(asp1, off);
            asp2 += __shfl_xor(asp2, off); asp3 += __shfl_xor(asp3, off);
            adp0 += __shfl_xor(adp0, off); adp1 += __shfl_xor(adp1, off);
            adp2 += __shfl_xor(adp2, off); adp3 += __shfl_xor(adp3, off);
        }
        if (lm == 0) {
            int grb = row0 + w * 16 + lg * 4;
            if (grb + 0 < N) { as_[grb + 0] = asp0; ad_[grb + 0] = adp0; }
            if (grb + 1 < N) { as_[grb + 1] = asp1; ad_[grb + 1] = adp1; }
            if (grb + 2 < N) { as_[grb + 2] = asp2; ad_[grb + 2] = adp2; }
            if (grb + 3 < N) { as_[grb + 3] = asp3; ad_[grb + 3] = adp3; }
        }
    }
}

// ---------------- layer 1 aggregation (+bias +ELU) ---------------- (R11 form)

__global__ void k_agg1(const ushortT* __restrict__ h1bf,
                       const float* __restrict__ as1, const float* __restrict__ ad1,
                       const int* __restrict__ offsets, const ushortT* __restrict__ csr,
                       const float* __restrict__ b1,
                       int N, ushortT* __restrict__ h2in) {
    int wid  = (blockIdx.x * blockDim.x + threadIdx.x) >> 6;
    int lane = threadIdx.x & 63;
    if (wid >= N) return;
    int v = wid;
    int hc = lane >> 3;
    int hp = lane & 7;
    float adc = ad1[v * H1N + hc];
    float adp = ad1[v * H1N + hp];
    float denom = 0.f, acc0 = 0.f, acc1 = 0.f;
    int beg = offsets[v], end = offsets[v + 1];
    int j = beg;
    for (; j + 8 <= end; j += 8) {
        int ep = lane >> 3;
        int sE = csr[j + ep];
        float a = as1[sE * H1N + hp];
        float pp = __expf(leaky(a + adp));
#pragma unroll
        for (int e = 0; e < 8; ++e) {
            int srcl = e * 8 + hc;
            float pe = __shfl(pp, srcl);
            int   se = __shfl(sE, srcl);
            unsigned q = *(const unsigned*)(h1bf + (size_t)se * IN_CH + lane * 2);
            denom += pe;
            acc0 = fmaf(pe, bf2f((ushortT)(q & 0xFFFFu)), acc0);
            acc1 = fmaf(pe, bf2f((ushortT)(q >> 16)), acc1);
        }
    }
    if (j + 4 <= end) {
        int ep = (lane >> 3) & 3;
        int sE = csr[j + ep];
        float a = as1[sE * H1N + hp];
        float pp = __expf(leaky(a + adp));
#pragma unroll
        for (int e = 0; e < 4; ++e) {
            int srcl = e * 8 + hc;
            float pe = __shfl(pp, srcl);
            int   se = __shfl(sE, srcl);
            unsigned q = *(const unsigned*)(h1bf + (size_t)se * IN_CH + lane * 2);
            denom += pe;
            acc0 = fmaf(pe, bf2f((ushortT)(q & 0xFFFFu)), acc0);
            acc1 = fmaf(pe, bf2f((ushortT)(q >> 16)), acc1);
        }
        j += 4;
    }
    for (; j < end; ++j) {
        int s = csr[j];
        float a = as1[s * H1N + hc];
        unsigned q = *(const unsigned*)(h1bf + (size_t)s * IN_CH + lane * 2);
        float p = __expf(leaky(a + adc));
        denom += p;
        acc0 = fmaf(p, bf2f((ushortT)(q & 0xFFFFu)), acc0);
        acc1 = fmaf(p, bf2f((ushortT)(q >> 16)), acc1);
    }
    float inv = 1.f / (denom + 1e-16f);
    float o0 = acc0 * inv + b1[lane * 2];
    float o1 = acc1 * inv + b1[lane * 2 + 1];
    o0 = (o0 > 0.f) ? o0 : expm1f(o0);
    o1 = (o1 > 0.f) ? o1 : expm1f(o1);
    unsigned pk = ((unsigned)f2bf(o1) << 16) | (unsigned)f2bf(o0);
    *(unsigned*)(h2in + (size_t)v * IN_CH + lane * 2) = pk;
}

// ---------------- layer 2 aggregation (+bias) + log_softmax ---------------- (R11 form)

__global__ __launch_bounds__(256) void k_agg2(const ushortT* __restrict__ h2bf,
                       const float* __restrict__ as2, const float* __restrict__ ad2,
                       const int* __restrict__ offsets, const ushortT* __restrict__ csr,
                       const float* __restrict__ b2,
                       int N, float* __restrict__ out) {
    int wid  = (blockIdx.x * blockDim.x + threadIdx.x) >> 6;
    int lane = threadIdx.x & 63;
    int half = lane >> 5;
    int v = wid * 2 + half;
    bool alive = (v < N);
    int c2 = (lane & 31) * 2;

    float ad = 0.f;
    int beg = 0, end = 0;
    if (alive) {
        ad = ad2[v];
        beg = offsets[v];
        end = offsets[v + 1];
    }
    float denom = 0.f, acc0 = 0.f, acc1 = 0.f;
    int j = beg;
    for (; j + 8 <= end; j += 8) {
        int sE = csr[j + (lane & 7)];
        float p = __expf(leaky(as2[sE] + ad));
#pragma unroll
        for (int e = 0; e < 8; ++e) {
            int srcl = (lane & 32) + e;
            float pe = __shfl(p, srcl);
            int   se = __shfl(sE, srcl);
            unsigned q = *(const unsigned*)(h2bf + (size_t)se * C2N + c2);
            denom += pe;
            acc0 = fmaf(pe, bf2f((ushortT)(q & 0xFFFFu)), acc0);
            acc1 = fmaf(pe, bf2f((ushortT)(q >> 16)), acc1);
        }
    }
    if (j < end) {
        int m = end - j;
        int ep = lane & 7;
        int sE = 0;
        float p = 0.f;
        if (ep < m) {
            sE = csr[j + ep];
            p = __expf(leaky(as2[sE] + ad));
        }
        for (int e = 0; e < m; ++e) {
            int srcl = (lane & 32) + e;
            float pe = __shfl(p, srcl);
            int   se = __shfl(sE, srcl);
            unsigned q = *(const unsigned*)(h2bf + (size_t)se * C2N + c2);
            denom += pe;
            acc0 = fmaf(pe, bf2f((ushortT)(q & 0xFFFFu)), acc0);
            acc1 = fmaf(pe, bf2f((ushortT)(q >> 16)), acc1);
        }
    }
    float inv = 1.f / (denom + 1e-16f);
    float o0 = acc0 * inv + b2[c2];
    float o1 = acc1 * inv + b2[c2 + 1];
    float mx = fmaxf(o0, o1);
#pragma unroll
    for (int off = 16; off >= 1; off >>= 1) mx = fmaxf(mx, __shfl_xor(mx, off));
    float se2 = __expf(o0 - mx) + __expf(o1 - mx);
#pragma unroll
    for (int off = 16; off >= 1; off >>= 1) se2 += __shfl_xor(se2, off);
    if (alive) {
        float lse = logf(se2);
        float2 ov; ov.x = o0 - mx - lse; ov.y = o1 - mx - lse;
        *(float2*)(out + (size_t)v * C2N + c2) = ov;
    }
}

// ---------------- launch ----------------

extern "C" void kernel_launch(void* const* d_in, const int* in_sizes, int n_in,
                              void* d_out, int out_size, void* d_ws, size_t ws_size,
                              hipStream_t stream) {
    const float* x      = (const float*)d_in[0];
    const int*   ei     = (const int*)d_in[1];
    const float* W1     = (const float*)d_in[2];
    const float* att_s1 = (const float*)d_in[3];
    const float* att_d1 = (const float*)d_in[4];
    const float* b1     = (const float*)d_in[5];
    const float* W2     = (const float*)d_in[6];
    const float* att_s2 = (const float*)d_in[7];
    const float* att_d2 = (const float*)d_in[8];
    const float* b2     = (const float*)d_in[9];

    int N = in_sizes[0] / IN_CH;
    int E = in_sizes[1] / 2;
    const int* srcA = ei;
    const int* dstA = ei + E;
    int Etot = E + N;
    int nb = (N + BKT_NODES - 1) >> BKT_SHIFT;

    char* p = (char*)d_ws;
    auto carve = [&](size_t bytes) {
        void* r = (void*)p;
        p += (bytes + 255) & ~(size_t)255;
        return r;
    };
    ushortT* h1bf = (ushortT*)carve((size_t)N * IN_CH * 2);
    ushortT* h2bf = (ushortT*)carve((size_t)N * C2N * 2);
    ushortT* h2in = (ushortT*)carve((size_t)N * IN_CH * 2);
    float* as1  = (float*)carve((size_t)N * H1N * 4);
    float* ad1  = (float*)carve((size_t)N * H1N * 4);
    float* as2  = (float*)carve((size_t)N * 4);
    float* ad2  = (float*)carve((size_t)N * 4);
    int* offsets     = (int*)carve((size_t)(N + 1) * 4);
    ushortT* csr     = (ushortT*)carve((size_t)(Etot + 32) * 2);
    int* cnt         = (int*)carve((size_t)nb * NBLK * 4);
    int* bucketTotal = (int*)carve((size_t)nb * 4);
    int* bBase       = (int*)carve((size_t)(nb + 1) * 4);
    unsigned* pair   = (unsigned*)carve((size_t)Etot * 4);

    // CSR build (deterministic counting sort; no global atomics)
    k_cnt<<<NBLK, 512, 0, stream>>>(srcA, dstA, E, N, cnt);
    k_scanrel<<<nb, NBLK, 0, stream>>>(cnt, bucketTotal);
    k_scanbucket<<<1, 512, 0, stream>>>(bucketTotal, nb, bBase, N, offsets);
    k_bin<<<NBLK, 512, 0, stream>>>(srcA, dstA, E, N, cnt, bBase, pair);
    k_csr_local<<<nb, 256, 0, stream>>>(pair, bBase, N, offsets, csr);

    // layer 1
    k_gemm_att<128, 8, false><<<(N + 63) / 64, 256, 0, stream>>>(x, W1, att_s1, att_d1,
                                                                 N, h1bf, as1, ad1);
    k_agg1<<<(N * 64 + 255) / 256, 256, 0, stream>>>(h1bf, as1, ad1, offsets, csr, b1, N, h2in);

    // layer 2
    k_gemm_att<64, 1, true><<<(N + 63) / 64, 256, 0, stream>>>(h2in, W2, att_s2, att_d2,
                                                               N, h2bf, as2, ad2);
    k_agg2<<<(N * 32 + 255) / 256, 256, 0, stream>>>(h2bf, as2, ad2, offsets, csr, b2,
                                                     N, (float*)d_out);
}